// Round 10
// baseline (46.633 us; speedup 1.0000x reference)
//
#include <hip/hip_runtime.h>

typedef short bf16x8 __attribute__((ext_vector_type(8)));
typedef float f32x16 __attribute__((ext_vector_type(16)));

static constexpr int KH = 15, KW = 15;
static constexpr int HI = 4096, WI = 4096;
static constexpr int HO = HI - KH + 1, WO = WI - KW + 1;   // 4082 x 4082
static constexpr int TM = 128, TN = 64;                    // output tile per block
static constexpr int LR   = 142;                           // TM + KH - 1 staged rows
static constexpr int LC   = 80;                            // staged bf16 cols (granule max col 79)
static constexpr int LSTR = 88;                            // 176 B/row: 16B-aligned; 44 dw %32 = 12 (benign, proven)
static constexpr int IPR  = LC / 4;                        // 20 float4 items/row
static constexpr int ITEMS = LR * IPR;                     // 2840
static constexpr int NSLOT = 23;                           // compact B slot table (slot 22 = natural zeros)
static constexpr int BKH   = NSLOT * 8;                    // 184 shorts per kh

__device__ __forceinline__ unsigned int f2bf(float f) {
  unsigned int u = __builtin_bit_cast(unsigned int, f);
  return (u + 0x7FFFu + ((u >> 16) & 1u)) >> 16;
}

__device__ __forceinline__ unsigned int cvt_pk_bf16(float lo, float hi) {
  unsigned int r;
  asm("v_cvt_pk_bf16_f32 %0, %1, %2" : "=v"(r) : "v"(lo), "v"(hi));
  return r;
}

#define MFMA32(a, b, c) __builtin_amdgcn_mfma_f32_32x32x16_bf16((a), (b), (c), 0, 0, 0)

__global__ __launch_bounds__(256, 5)
void conv2d_pipe(const float* __restrict__ x, const float* __restrict__ w,
                 const float* __restrict__ bias, float* __restrict__ out) {
  __shared__ unsigned short sx[LR * LSTR];        // 24,992 B bf16 input tile
  __shared__ unsigned short btab[KH * BKH];       //  5,520 B compact sliding-window weights
  // total 30,512 B -> 5 blocks/CU (20 waves/CU), 1 wave/SIMD per block

  const int tid = threadIdx.x;

  // XCD-aware bijective swizzle (2048 blocks, %8==0). Within an XCD: a
  // contiguous 4-tile-row band (L2 halo reuse).
  const int bid0 = blockIdx.y * gridDim.x + blockIdx.x;
  const int bid  = (bid0 & 7) * 256 + (bid0 >> 3);
  const int row0 = (bid >> 6) * TM;
  const int col0 = (bid & 63) * TN;

  // ---- compact B table: btab[kh][s][t] = w[kh, s-7+t] if 0 <= s-7+t < 15 else 0
  for (int i = tid; i < KH * NSLOT; i += 256) {
    const int kh = i / NSLOT;
    const int s  = i - kh * NSLOT;
    const int e0 = s - 7;
    unsigned int dw[4];
    #pragma unroll
    for (int t2 = 0; t2 < 4; ++t2) {
      const int c0 = e0 + 2 * t2;
      const int c1 = c0 + 1;
      const unsigned int b0 = (c0 >= 0 && c0 < KW) ? f2bf(w[kh * KW + c0]) : 0u;
      const unsigned int b1 = (c1 >= 0 && c1 < KW) ? f2bf(w[kh * KW + c1]) : 0u;
      dw[t2] = b0 | (b1 << 16);
    }
    *(uint4*)&btab[i * 8] = make_uint4(dw[0], dw[1], dw[2], dw[3]);
  }

  // ---- stage 142 x 80 input tile as bf16 (zero-fill OOB halo) ----
  for (int i = tid; i < ITEMS; i += 256) {
    const int r  = i / IPR;
    const int c4 = (i - r * IPR) * 4;
    const int gr = row0 + r;
    const int gc = col0 + c4;
    float4 v = make_float4(0.f, 0.f, 0.f, 0.f);
    if (gr < HI) {
      const float* p = &x[(long)gr * WI + gc];
      if (gc + 3 < WI) {
        v = *(const float4*)p;
      } else {
        if (gc + 0 < WI) v.x = p[0];
        if (gc + 1 < WI) v.y = p[1];
        if (gc + 2 < WI) v.z = p[2];
        if (gc + 3 < WI) v.w = p[3];
      }
    }
    *(uint2*)&sx[r * LSTR + c4] = make_uint2(cvt_pk_bf16(v.x, v.y), cvt_pk_bf16(v.z, v.w));
  }

  const float bs = bias[0];
  __syncthreads();

  // ---- per-wave setup: wave g = row-group (rows 32g..32g+31), cols 0..63 (2 tiles) ----
  const int lane = tid & 63;
  const int g    = tid >> 6;                  // 0..3
  const int n    = lane & 31;                 // A row-lane / B col / out col within tile
  const int kg   = lane >> 5;                 // k-group: k = 8*kg + t

  // A granule u (u=0..4): x[32g + n + kh, 16u + 8kg + t]
  const unsigned short* abase = &sx[(32 * g + n) * LSTR + 8 * kg];
  // B sigma reads: slot e0 = 16*sigma + 8*kg - n, clamped to zero-slot 22
  const int e0k = 8 * kg - n;
  const int s0  = (e0k >= -7) ? e0k + 7 : 22;
  const int s1  = (e0k >= -23 && e0k <= -2) ? e0k + 23 : 22;
  const int s2  = (e0k <= -18) ? e0k + 39 : 22;
  const unsigned short* bp0 = &btab[s0 * 8];
  const unsigned short* bp1 = &btab[s1 * 8];
  const unsigned short* bp2 = &btab[s2 * 8];

  f32x16 acc0, acc1;
  #pragma unroll
  for (int r = 0; r < 16; ++r) { acc0[r] = bs; acc1[r] = bs; }

  // ---- pipelined main loop ----
  // prologue: prefetch kh=0's leading operands
  bf16x8 A0 = *(const bf16x8*)(abase + 0);
  bf16x8 A1 = *(const bf16x8*)(abase + 16);
  bf16x8 B0 = *(const bf16x8*)(bp0);
  bf16x8 B1 = *(const bf16x8*)(bp1);
  bf16x8 B2 = *(const bf16x8*)(bp2);

  #pragma unroll
  for (int kh = 0; kh < KH; ++kh) {
    const unsigned short* ar = abase + kh * LSTR;
    // current-kh trailing granules (first in issue order -> shortest lgkm wait)
    const bf16x8 A2 = *(const bf16x8*)(ar + 32);
    const bf16x8 A3 = *(const bf16x8*)(ar + 48);
    const bf16x8 A4 = *(const bf16x8*)(ar + 64);
    // next-kh leading operands (issued behind; consumed next iteration)
    bf16x8 nA0, nA1, nB0, nB1, nB2;
    if (kh + 1 < KH) {
      const unsigned short* arn = ar + LSTR;
      nA0 = *(const bf16x8*)(arn + 0);
      nA1 = *(const bf16x8*)(arn + 16);
      nB0 = *(const bf16x8*)(bp0 + (kh + 1) * BKH);
      nB1 = *(const bf16x8*)(bp1 + (kh + 1) * BKH);
      nB2 = *(const bf16x8*)(bp2 + (kh + 1) * BKH);
    }
    __builtin_amdgcn_s_setprio(1);
    acc0 = MFMA32(A0, B0, acc0);     // prefetched: no wait
    acc0 = MFMA32(A1, B1, acc0);
    acc0 = MFMA32(A2, B2, acc0);
    acc1 = MFMA32(A2, B0, acc1);
    acc1 = MFMA32(A3, B1, acc1);
    acc1 = MFMA32(A4, B2, acc1);
    __builtin_amdgcn_s_setprio(0);
    if (kh + 1 < KH) { A0 = nA0; A1 = nA1; B0 = nB0; B1 = nB1; B2 = nB2; }
  }

  // ---- epilogue: 32x32 C/D layout col = lane&31, row = (reg&3) + 8*(reg>>2) + 4*kg ----
  const int oc  = col0 + n;
  const int orb = row0 + 32 * g + 4 * kg;
  #pragma unroll
  for (int r = 0; r < 16; ++r) {
    const int orow = orb + (r & 3) + 8 * (r >> 2);
    if (orow < HO) {
      if (oc < WO)      out[(long)orow * WO + oc]      = acc0[r];
      if (oc + 32 < WO) out[(long)orow * WO + oc + 32] = acc1[r];
    }
  }
}

extern "C" void kernel_launch(void* const* d_in, const int* in_sizes, int n_in,
                              void* d_out, int out_size, void* d_ws, size_t ws_size,
                              hipStream_t stream) {
  const float* x    = (const float*)d_in[0];
  const float* w    = (const float*)d_in[1];
  const float* bias = (const float*)d_in[2];
  float* out        = (float*)d_out;

  dim3 grid(64, 32);   // 2048 blocks of 128x64 tiles; 5 resident/CU
  conv2d_pipe<<<grid, dim3(256, 1, 1), 0, stream>>>(x, w, bias, out);
}

// Round 11
// 34.940 us; speedup vs baseline: 1.3347x; 1.3347x over previous
//
#include <hip/hip_runtime.h>

typedef short bf16x8 __attribute__((ext_vector_type(8)));
typedef float f32x4  __attribute__((ext_vector_type(4)));

static constexpr int KH = 15, KW = 15;
static constexpr int HI = 4096, WI = 4096;
static constexpr int HO = HI - KH + 1, WO = WI - KW + 1;   // 4082 x 4082
static constexpr int TM = 64, TN = 128;                    // output tile
static constexpr int NT = 2;                               // tiles marched per block (vertical)
static constexpr int LR   = TM + KH - 1;                   // 78 staged rows
static constexpr int LC   = 144;                           // staged bf16 cols
static constexpr int LSTR = 152;                           // 304 B/row: 16B-aligned
static constexpr int IPR   = LC / 4;                       // 36 float4 items/row
static constexpr int ITEMS = LR * IPR;                     // 2808
static constexpr int SITER = (ITEMS + 511) / 512;          // 6 per thread
static constexpr int NSLOT = 23;                           // compact B slot table (slot 22 = zeros)
static constexpr int BKH   = NSLOT * 8;                    // 184 shorts per kh

__device__ __forceinline__ unsigned int f2bf(float f) {
  unsigned int u = __builtin_bit_cast(unsigned int, f);
  return (u + 0x7FFFu + ((u >> 16) & 1u)) >> 16;
}

__device__ __forceinline__ unsigned int cvt_pk_bf16(float lo, float hi) {
  unsigned int r;
  asm("v_cvt_pk_bf16_f32 %0, %1, %2" : "=v"(r) : "v"(lo), "v"(hi));
  return r;
}

__device__ __forceinline__ float4 load_item(const float* __restrict__ x,
                                            int row0, int col0, int it) {
  float4 v = make_float4(0.f, 0.f, 0.f, 0.f);
  if (it < ITEMS) {
    const int r  = it / IPR;
    const int c4 = (it - r * IPR) * 4;
    const int gr = row0 + r;
    const int gc = col0 + c4;
    if (gr < HI) {
      const float* p = &x[(long)gr * WI + gc];
      if (gc + 3 < WI) {
        v = *(const float4*)p;
      } else {
        if (gc + 0 < WI) v.x = p[0];
        if (gc + 1 < WI) v.y = p[1];
        if (gc + 2 < WI) v.z = p[2];
        if (gc + 3 < WI) v.w = p[3];
      }
    }
  }
  return v;
}

__device__ __forceinline__ void write_item(unsigned short* sx, int it, float4 v) {
  if (it < ITEMS) {
    const int r  = it / IPR;
    const int c4 = (it - r * IPR) * 4;
    *(uint2*)&sx[r * LSTR + c4] = make_uint2(cvt_pk_bf16(v.x, v.y), cvt_pk_bf16(v.z, v.w));
  }
}

#define MFMA16(a, b, c) __builtin_amdgcn_mfma_f32_16x16x32_bf16((a), (b), (c), 0, 0, 0)

__global__ __launch_bounds__(512, 4)
void conv2d_m2(const float* __restrict__ x, const float* __restrict__ w,
               const float* __restrict__ bias, float* __restrict__ out) {
  __shared__ unsigned short sx[LR * LSTR];        // 23,712 B single-buffer input tile
  __shared__ unsigned short btab[KH * BKH];       //  5,520 B compact clamp-slot weights
  // total 29,232 B -> LDS no longer the occupancy limiter (thread cap: 4 blocks/CU, 32 waves)

  const int tid = threadIdx.x;

  // XCD-aware bijective swizzle (1024 blocks, 1024 % 8 == 0)
  const int bid0  = blockIdx.y * gridDim.x + blockIdx.x;
  const int bid   = (bid0 & 7) * 128 + (bid0 >> 3);
  const int col0  = (bid & 31) * TN;
  const int rbase = (bid >> 5) * (NT * TM);

  // ---- compact B table: btab[kh][s][t] = w[kh, s-7+t] if 0 <= s-7+t < 15 else 0
  //      (slot 22 = all zeros; broadcast-heavy reads -> conflict-free)
  for (int i = tid; i < KH * NSLOT; i += 512) {
    const int kh = i / NSLOT;
    const int s  = i - kh * NSLOT;
    const int e0 = s - 7;
    unsigned int dw[4];
    #pragma unroll
    for (int t2 = 0; t2 < 4; ++t2) {
      const int c0 = e0 + 2 * t2;
      const int c1 = c0 + 1;
      const unsigned int b0 = (c0 >= 0 && c0 < KW) ? f2bf(w[kh * KW + c0]) : 0u;
      const unsigned int b1 = (c1 >= 0 && c1 < KW) ? f2bf(w[kh * KW + c1]) : 0u;
      dw[t2] = b0 | (b1 << 16);
    }
    *(uint4*)&btab[i * 8] = make_uint4(dw[0], dw[1], dw[2], dw[3]);
  }

  // ---- stage tile 0 ----
  {
    float4 v0_[SITER];
    #pragma unroll
    for (int k = 0; k < SITER; ++k) v0_[k] = load_item(x, rbase, col0, tid + 512 * k);
    #pragma unroll
    for (int k = 0; k < SITER; ++k) write_item(sx, tid + 512 * k, v0_[k]);
  }
  const float bs = bias[0];
  __syncthreads();

  // ---- per-wave setup: wave wv -> output cols [wv*16, wv*16+16) ----
  const int lane = tid & 63;
  const int wv   = tid >> 6;
  const int q    = lane & 15;                      // A row id / B col / out col
  const int kg4  = lane >> 4;                      // k-group: k = 8*kg4 + t
  const unsigned short* abase = &sx[q * LSTR + wv * 16 + kg4 * 8];
  // B slot: need w[kh, 8*kg4 - q + t]; e = 8*kg4 - q in [-15, 24], clamp to zero-slot 22
  const int e    = 8 * kg4 - q;
  const int s    = (e >= -7 && e <= 14) ? e + 7 : 22;
  const unsigned short* bbase = &btab[s * 8];
  const int ocol = col0 + wv * 16 + q;

  #pragma unroll
  for (int t = 0; t < NT; ++t) {
    const int row0 = rbase + t * TM;

    // issue next tile's loads; they land during the MFMA phase below
    float4 nv[SITER];
    if (t + 1 < NT) {
      #pragma unroll
      for (int k = 0; k < SITER; ++k)
        nv[k] = load_item(x, row0 + TM, col0, tid + 512 * k);
    }

    // compute current tile: per kh = 1 broadcast B-read + 4 A-reads + 4 independent MFMAs
    f32x4 acc0 = {bs,bs,bs,bs}, acc1 = {bs,bs,bs,bs};
    f32x4 acc2 = {bs,bs,bs,bs}, acc3 = {bs,bs,bs,bs};
    __builtin_amdgcn_s_setprio(1);
    #pragma unroll
    for (int kh = 0; kh < 15; ++kh) {
      const bf16x8 b = *(const bf16x8*)(bbase + kh * BKH);
      const unsigned short* ar = abase + kh * LSTR;
      acc0 = MFMA16(*(const bf16x8*)(ar + 0  * LSTR), b, acc0);
      acc1 = MFMA16(*(const bf16x8*)(ar + 16 * LSTR), b, acc1);
      acc2 = MFMA16(*(const bf16x8*)(ar + 32 * LSTR), b, acc2);
      acc3 = MFMA16(*(const bf16x8*)(ar + 48 * LSTR), b, acc3);
    }
    __builtin_amdgcn_s_setprio(0);

    // store: C/D layout col=lane&15, row=(lane>>4)*4+reg
    if (ocol < WO) {
      const int orb = row0 + kg4 * 4;
      const f32x4 av[4] = {acc0, acc1, acc2, acc3};
      #pragma unroll
      for (int m = 0; m < 4; ++m) {
        #pragma unroll
        for (int r = 0; r < 4; ++r) {
          const int orow = orb + 16 * m + r;
          if (orow < HO) out[(long)orow * WO + ocol] = av[m][r];
        }
      }
    }

    // rotate the single LDS buffer for the next tile
    if (t + 1 < NT) {
      __syncthreads();                              // everyone done reading sx
      #pragma unroll
      for (int k = 0; k < SITER; ++k) write_item(sx, tid + 512 * k, nv[k]);
      __syncthreads();                              // next tile visible
    }
  }
}

extern "C" void kernel_launch(void* const* d_in, const int* in_sizes, int n_in,
                              void* d_out, int out_size, void* d_ws, size_t ws_size,
                              hipStream_t stream) {
  const float* x    = (const float*)d_in[0];
  const float* w    = (const float*)d_in[1];
  const float* bias = (const float*)d_in[2];
  float* out        = (float*)d_out;

  dim3 grid(32, 32);   // 1024 blocks: 32 col-strips x 32 row-bands (2 tiles each)
  conv2d_m2<<<grid, dim3(512, 1, 1), 0, stream>>>(x, w, bias, out);
}